// Round 7
// baseline (307.263 us; speedup 1.0000x reference)
//
#include <hip/hip_runtime.h>

// ---------------------------------------------------------------------------
// MaskedMultiHeadAttention: B=2, T=2048, E=1024, H=16, D=64, WINDOW=256
//
// R7: R6's global->VGPR->LDS staged GEMM, but with __launch_bounds__(256,2)
// so the register allocator keeps the prefetch registers live (R6 spilled:
// VGPR 76, WRITE_SIZE 419 MB of scratch traffic). Prologue: inline dtype
// detect, fused canon, fused transposes (5 launches total).
// ---------------------------------------------------------------------------

typedef __bf16 bf16_t;
typedef bf16_t bf16x8 __attribute__((ext_vector_type(8)));
typedef bf16_t bf16x4 __attribute__((ext_vector_type(4)));
typedef float  floatx4 __attribute__((ext_vector_type(4)));

#define SEQ_T   2048
#define NHEAD   16
#define HDIM    64
#define EMB     1024
#define WIN     256
#define SCALE_F 0.125f

// ---------------------------------------------------------------------------
// Wave-uniform dtype detect: all waves read the same 1 KB of hidden.
// bf16 -> low-16 exponent near 127 (~99% in [100,150]); fp32 -> ~20%.
// ---------------------------------------------------------------------------
__device__ __forceinline__ int detect_bf16(const uint4* __restrict__ det)
{
    const int lane = threadIdx.x & 63;
    const uint4 v = det[lane];
    int c = 0;
    #pragma unroll
    for (int e = 0; e < 4; ++e) {
        const unsigned int ex = ((&v.x)[e] >> 7) & 0xffu;
        c += (ex >= 100u && ex <= 150u) ? 1 : 0;
    }
    #pragma unroll
    for (int m = 32; m >= 1; m >>= 1) c += __shfl_xor(c, m, 64);
    return (c * 2 > 256) ? 1 : 0;
}

// ---------------------------------------------------------------------------
// canon_all: only does work when inputs are fp32 (flag==0).
// blocks 0..4095: hidden -> Hc; 4096..4098: b_attn; 4099: b_proj.
// ---------------------------------------------------------------------------
__global__ __launch_bounds__(256) void canon_all(
    const void* __restrict__ hidden, bf16_t* __restrict__ Hc,
    const void* __restrict__ ba, bf16_t* __restrict__ bba,
    const void* __restrict__ bp, bf16_t* __restrict__ bbp)
{
    if (detect_bf16((const uint4*)hidden)) return;
    const int blk = blockIdx.x;
    const float* src;
    bf16_t* dst;
    int base;
    if (blk < 4096)      { src = (const float*)hidden; dst = Hc;  base = blk * 1024; }
    else if (blk < 4099) { src = (const float*)ba;     dst = bba; base = (blk - 4096) * 1024; }
    else                 { src = (const float*)bp;     dst = bbp; base = 0; }
    const int i4 = base + threadIdx.x * 4;
    const float4 x = *(const float4*)(src + i4);
    bf16x4 v;
    v[0] = (bf16_t)x.x; v[1] = (bf16_t)x.y;
    v[2] = (bf16_t)x.z; v[3] = (bf16_t)x.w;
    *(bf16x4*)(dst + i4) = v;
}

// ---------------------------------------------------------------------------
// Both weight transposes in one launch. blocks 0..767: w_attn (N=3072);
// 768..1023: w_proj (N=1024). Wt[n][k] = (bf16)W[k][n].
// ---------------------------------------------------------------------------
__global__ __launch_bounds__(256) void transpose_both(
    const void* __restrict__ wA, bf16_t* __restrict__ WtA,
    const void* __restrict__ wP, bf16_t* __restrict__ WtP,
    const uint4* __restrict__ det)
{
    __shared__ __align__(16) bf16_t tile[64][68];
    const int f = detect_bf16(det);
    int id = blockIdx.x;
    const void* W; bf16_t* Wt; int N, bx, by;
    if (id < 768) { W = wA; Wt = WtA; N = 3072; bx = id % 48; by = id / 48; }
    else { id -= 768; W = wP; Wt = WtP; N = 1024; bx = id % 16; by = id / 16; }
    const int K = 1024;
    const int n0 = bx * 64;
    const int k0 = by * 64;
    const int tx = threadIdx.x & 15;
    const int ty = threadIdx.x >> 4;

    #pragma unroll
    for (int r = ty; r < 64; r += 16) {
        bf16x4 v;
        const size_t base = (size_t)(k0 + r) * N + n0 + tx * 4;
        if (f) {
            v = *(const bf16x4*)((const bf16_t*)W + base);
        } else {
            const float4 x = *(const float4*)((const float*)W + base);
            v[0] = (bf16_t)x.x; v[1] = (bf16_t)x.y;
            v[2] = (bf16_t)x.z; v[3] = (bf16_t)x.w;
        }
        *(bf16x4*)&tile[r][tx * 4] = v;
    }
    __syncthreads();
    #pragma unroll
    for (int r = ty; r < 64; r += 16) {
        bf16x4 v;
        v[0] = tile[tx * 4 + 0][r];
        v[1] = tile[tx * 4 + 1][r];
        v[2] = tile[tx * 4 + 2][r];
        v[3] = tile[tx * 4 + 3][r];
        *(bf16x4*)(Wt + (size_t)(n0 + r) * K + k0 + tx * 4) = v;
    }
}

// ---------------------------------------------------------------------------
// C[M][N] = A[M][K] @ Bt[N][K]^T + bias[N]   (bf16 in, fp32 accumulate)
// Staging: tile k+1 -> VGPRs (coalesced dwordx4) issued before tile k's
// compute; VGPR -> LDS via swizzled ds_write_b128 (slot s = g ^ (row&7),
// row stride 128 B — conflict-free fragment reads, verified R5).
// __launch_bounds__(256,2): VGPR cap ~256 so the prefetch regs DON'T spill
// (R6's default bounds spilled -> 419 MB scratch writes).
// ---------------------------------------------------------------------------
template<int BNt>
__global__ __launch_bounds__(256, 2) void gemm_bt_bias(
    const bf16_t* __restrict__ Abf,   // used when flag==1 (bf16 input)
    const bf16_t* __restrict__ Aalt,  // used when flag==0 (canonicalized)
    const bf16_t* __restrict__ Bt,
    const bf16_t* __restrict__ biasbf,
    const bf16_t* __restrict__ biasalt,
    void* __restrict__ C,
    int M, int N, int K,
    int force_bf16, const uint4* __restrict__ det)
{
    constexpr int BMt = 128;
    constexpr int NF  = BNt / 32;     // n-frags per wave (wave tile = 64 x BNt/2)
    constexpr int NB  = BNt / 32;     // B staging chunks per thread
    __shared__ __align__(16) bf16_t As[BMt * 64];   // 16 KB
    __shared__ __align__(16) bf16_t Bs[BNt * 64];   // 16 or 8 KB

    const int flag = detect_bf16(det);
    const bf16_t* A    = flag ? Abf    : Aalt;
    const bf16_t* bias = flag ? biasbf : biasalt;
    const int obf = force_bf16 | flag;

    const int tid  = threadIdx.x;
    const int wave = tid >> 6;
    const int lane = tid & 63;
    const int quad = lane >> 4;
    const int n16  = lane & 15;
    const int m0 = blockIdx.y * BMt;
    const int n0 = blockIdx.x * BNt;
    const int wm = (wave >> 1) * 64;
    const int wn = (wave & 1) * (BNt / 2);

    floatx4 acc[4][NF] = {};

    uint4 rA[4], rB[NB];

    // A: thread t covers row t>>1, 64 contiguous bytes at col (t&1)*32 elems
    const int arow = tid >> 1;
    const int acol = (tid & 1) * 32;
    // B: BNt=128 same as A; BNt=64: row t>>2, 32 B at (t&3)*16 elems
    const int brow = (BNt == 128) ? (tid >> 1) : (tid >> 2);
    const int bcol = (BNt == 128) ? ((tid & 1) * 32) : ((tid & 3) * 16);

    auto loadA = [&](int kk) {
        const bf16_t* g = A + (size_t)(m0 + arow) * K + kk + acol;
        #pragma unroll
        for (int i = 0; i < 4; ++i) rA[i] = *(const uint4*)(g + i * 8);
    };
    auto loadB = [&](int kk) {
        const bf16_t* g = Bt + (size_t)(n0 + brow) * K + kk + bcol;
        #pragma unroll
        for (int i = 0; i < NB; ++i) rB[i] = *(const uint4*)(g + i * 8);
    };
    auto storeA = [&]() {
        #pragma unroll
        for (int i = 0; i < 4; ++i) {
            const int g = (acol >> 3) + i;            // global chunk 0..7
            const int s = g ^ (arow & 7);             // swizzled slot
            *(uint4*)(As + arow * 64 + s * 8) = rA[i];
        }
    };
    auto storeB = [&]() {
        #pragma unroll
        for (int i = 0; i < NB; ++i) {
            const int g = (bcol >> 3) + i;
            const int s = g ^ (brow & 7);
            *(uint4*)(Bs + brow * 64 + s * 8) = rB[i];
        }
    };

    loadA(0); loadB(0);

    for (int k0 = 0; k0 < K; k0 += 64) {
        __syncthreads();                  // LDS free (prev compute done)
        storeA(); storeB();               // consumes tile-k regs (in flight ~1 iter)
        if (k0 + 64 < K) { loadA(k0 + 64); loadB(k0 + 64); }  // fly during compute
        __syncthreads();                  // ds_writes visible

        #pragma unroll
        for (int s = 0; s < 2; ++s) {
            const int ch = (((4 * s + quad) ^ (n16 & 7)) * 8);
            const bf16_t* pa = As + (wm + n16) * 64 + ch;
            const bf16_t* pb = Bs + (wn + n16) * 64 + ch;
            bf16x8 af[4], bfr[NF];
            #pragma unroll
            for (int ff = 0; ff < 4; ++ff)
                af[ff] = *(const bf16x8*)(pa + ff * 16 * 64);
            #pragma unroll
            for (int ff = 0; ff < NF; ++ff)
                bfr[ff] = *(const bf16x8*)(pb + ff * 16 * 64);
            #pragma unroll
            for (int mf = 0; mf < 4; ++mf)
                #pragma unroll
                for (int nf = 0; nf < NF; ++nf)
                    acc[mf][nf] = __builtin_amdgcn_mfma_f32_16x16x32_bf16(
                        af[mf], bfr[nf], acc[mf][nf], 0, 0, 0);
        }
    }

    const int col   = n0 + wn + n16;
    const int rbase = m0 + wm + quad * 4;
    #pragma unroll
    for (int nf = 0; nf < NF; ++nf) {
        const float bv = (float)bias[col + nf * 16];
        #pragma unroll
        for (int mf = 0; mf < 4; ++mf) {
            #pragma unroll
            for (int r = 0; r < 4; ++r) {
                const size_t idx =
                    (size_t)(rbase + mf * 16 + r) * N + col + nf * 16;
                const float val = acc[mf][nf][r] + bv;
                if (obf) ((bf16_t*)C)[idx] = (bf16_t)val;
                else     ((float*)C)[idx]  = val;
            }
        }
    }
}

// ---------------------------------------------------------------------------
// MFMA flash attention (verified R3, unchanged). Block = (b,h,64-query tile).
// ---------------------------------------------------------------------------
#define CW   160
#define VT_S 168
#define P_S  168

__global__ __launch_bounds__(256) void attn_mfma(
    const bf16_t* __restrict__ qkv,
    bf16_t* __restrict__ attn_out)
{
    __shared__ __align__(16) bf16_t Ks[CW * 64];       // 20480 B
    __shared__ __align__(16) bf16_t Vt[64 * VT_S];     // 21504 B
    __shared__ __align__(16) bf16_t Pst[4][16 * P_S];  // 21504 B

    const int tid  = threadIdx.x;
    const int wave = tid >> 6;
    const int lane = tid & 63;
    const int quad = lane >> 4;
    const int n16  = lane & 15;

    const int i0 = blockIdx.x * 64;
    const int h  = blockIdx.y;
    const int b  = blockIdx.z;
    const size_t rowbase = (size_t)b * SEQ_T;
    const int kbase  = i0 - 256;
    const int iw     = 16 * wave;
    const int climit = 256 - i0;

    const bf16_t* Qg = qkv + (rowbase + i0 + iw + n16) * (3 * EMB) + h * HDIM;
    bf16x8 qf[2];
    qf[0] = *(const bf16x8*)(Qg + quad * 8);
    qf[1] = *(const bf16x8*)(Qg + 32 + quad * 8);

    floatx4 Oac[4] = {};
    float m_run[4], l_run[4];
    #pragma unroll
    for (int rr = 0; rr < 4; ++rr) { m_run[rr] = -3.0e38f; l_run[rr] = 0.f; }

    for (int hc = 0; hc < 2; ++hc) {
        const int cbase = hc * CW;

        bf16x8 vreg[5];
        #pragma unroll
        for (int t = 0; t < 5; ++t) {
            const int idx = tid + 256 * t;
            const int lc  = idx >> 3;
            const int d0  = (idx & 7) * 8;
            int j = kbase + cbase + lc; if (j < 0) j = 0;
            vreg[t] = *(const bf16x8*)(qkv + (rowbase + j) * (3 * EMB)
                                       + 2 * EMB + h * HDIM + d0);
        }

        __syncthreads();

        #pragma unroll
        for (int t = 0; t < 5; ++t) {
            const int lc0 = wave * 40 + t * 8;
            const int lcL = lc0 + (lane >> 3);
            int j = kbase + cbase + lcL; if (j < 0) j = 0;
            const int g = (lane & 7) ^ (lcL & 7);
            const bf16_t* src = qkv + (rowbase + j) * (3 * EMB)
                                + EMB + h * HDIM + g * 8;
            __builtin_amdgcn_global_load_lds(
                (const __attribute__((address_space(1))) void*)src,
                (__attribute__((address_space(3))) void*)(Ks + lc0 * 64),
                16, 0, 0);
        }

        #pragma unroll
        for (int t = 0; t < 5; ++t) {
            const int idx = tid + 256 * t;
            const int lc  = idx >> 3;
            const int d0  = (idx & 7) * 8;
            #pragma unroll
            for (int e = 0; e < 8; ++e)
                Vt[(d0 + e) * VT_S + lc] = vreg[t][e];
        }

        __syncthreads();

        floatx4 sc[10];
        #pragma unroll
        for (int tt = 0; tt < 10; ++tt) {
            sc[tt] = (floatx4){0.f, 0.f, 0.f, 0.f};
            #pragma unroll
            for (int s2 = 0; s2 < 2; ++s2) {
                const int lc = 16 * tt + n16;
                const int ch = (4 * s2 + quad) ^ (lc & 7);
                const bf16x8 kf = *(const bf16x8*)(Ks + lc * 64 + ch * 8);
                sc[tt] = __builtin_amdgcn_mfma_f32_16x16x32_bf16(
                    qf[s2], kf, sc[tt], 0, 0, 0);
            }
        }

        #pragma unroll
        for (int tt = 0; tt < 10; ++tt) {
            const int c  = cbase + 16 * tt + n16;
            const int cw = c - iw;
            #pragma unroll
            for (int rr = 0; rr < 4; ++rr) {
                const int r = quad * 4 + rr;
                const bool valid = (cw > r) && (cw <= r + 256) && (c >= climit);
                sc[tt][rr] = valid ? sc[tt][rr] * SCALE_F : -3.0e38f;
            }
        }

        float cm[4];
        #pragma unroll
        for (int rr = 0; rr < 4; ++rr) {
            cm[rr] = -3.0e38f;
            #pragma unroll
            for (int tt = 0; tt < 10; ++tt) cm[rr] = fmaxf(cm[rr], sc[tt][rr]);
            #pragma unroll
            for (int m = 8; m >= 1; m >>= 1)
                cm[rr] = fmaxf(cm[rr], __shfl_xor(cm[rr], m, 64));
        }

        #pragma unroll
        for (int rr = 0; rr < 4; ++rr) {
            const float mnew  = fmaxf(m_run[rr], cm[rr]);
            const float alpha = __expf(m_run[rr] - mnew);
            m_run[rr] = mnew;
            l_run[rr] *= alpha;
            #pragma unroll
            for (int nt = 0; nt < 4; ++nt) Oac[nt][rr] *= alpha;
        }

        float psum[4] = {0.f, 0.f, 0.f, 0.f};
        #pragma unroll
        for (int tt = 0; tt < 10; ++tt) {
            #pragma unroll
            for (int rr = 0; rr < 4; ++rr) {
                const float s = sc[tt][rr];
                const float e = (s > -1.0e38f) ? __expf(s - m_run[rr]) : 0.f;
                psum[rr] += e;
                Pst[wave][(quad * 4 + rr) * P_S + 16 * tt + n16] = (bf16_t)e;
            }
        }
        #pragma unroll
        for (int rr = 0; rr < 4; ++rr) {
            #pragma unroll
            for (int m = 8; m >= 1; m >>= 1)
                psum[rr] += __shfl_xor(psum[rr], m, 64);
            l_run[rr] += psum[rr];
        }

        __syncthreads();

        #pragma unroll
        for (int ks = 0; ks < 5; ++ks) {
            const bf16x8 paf = *(const bf16x8*)(
                &Pst[wave][n16 * P_S + ks * 32 + quad * 8]);
            #pragma unroll
            for (int nt = 0; nt < 4; ++nt) {
                const bf16x8 vbf = *(const bf16x8*)(
                    Vt + (nt * 16 + n16) * VT_S + ks * 32 + quad * 8);
                Oac[nt] = __builtin_amdgcn_mfma_f32_16x16x32_bf16(
                    paf, vbf, Oac[nt], 0, 0, 0);
            }
        }
    }

    #pragma unroll
    for (int rr = 0; rr < 4; ++rr) {
        const float rden = 1.0f / l_run[rr];
        const size_t row = rowbase + i0 + iw + quad * 4 + rr;
        #pragma unroll
        for (int nt = 0; nt < 4; ++nt) {
            attn_out[row * EMB + h * HDIM + nt * 16 + n16] =
                (bf16_t)(Oac[nt][rr] * rden);
        }
    }
}

// ---------------------------------------------------------------------------
extern "C" void kernel_launch(void* const* d_in, const int* in_sizes, int n_in,
                              void* d_out, int out_size, void* d_ws, size_t ws_size,
                              hipStream_t stream)
{
    const void* hidden = d_in[0];
    const void* w_attn = d_in[1];
    const void* b_attn = d_in[2];
    const void* w_proj = d_in[3];
    const void* b_proj = d_in[4];

    char* ws = (char*)d_ws;
    bf16_t* Wt_attn = (bf16_t*)(ws);                       // [3072][1024]
    bf16_t* Wt_proj = (bf16_t*)(ws + (6u << 20));          // [1024][1024]
    bf16_t* qkv     = (bf16_t*)(ws + (8u << 20));          // [4096][3072]
    bf16_t* attn_o  = (bf16_t*)(ws + (32u << 20));         // [4096][1024]
    bf16_t* Hc      = (bf16_t*)(ws + (40u << 20));         // [4096][1024]
    bf16_t* bb_attn = (bf16_t*)(ws + (48u << 20));
    bf16_t* bb_proj = (bf16_t*)(ws + (48u << 20) + 8192);

    const uint4* det = (const uint4*)hidden;

    canon_all<<<4100, 256, 0, stream>>>(hidden, Hc, b_attn, bb_attn,
                                        b_proj, bb_proj);

    transpose_both<<<1024, 256, 0, stream>>>(w_attn, Wt_attn,
                                             w_proj, Wt_proj, det);

    gemm_bt_bias<128><<<dim3(3072 / 128, 4096 / 128), 256, 0, stream>>>(
        (const bf16_t*)hidden, Hc, Wt_attn,
        (const bf16_t*)b_attn, bb_attn, qkv, 4096, 3072, 1024, 1, det);

    attn_mfma<<<dim3(SEQ_T / 64, NHEAD, 2), 256, 0, stream>>>(qkv, attn_o);

    gemm_bt_bias<64><<<dim3(1024 / 64, 4096 / 128), 256, 0, stream>>>(
        attn_o, attn_o, Wt_proj,
        (const bf16_t*)b_proj, bb_proj, (void*)d_out, 4096, 1024, 1024, 0, det);
}

// Round 8
// 173.901 us; speedup vs baseline: 1.7669x; 1.7669x over previous
//
#include <hip/hip_runtime.h>

// ---------------------------------------------------------------------------
// MaskedMultiHeadAttention: B=2, T=2048, E=1024, H=16, D=64, WINDOW=256
//
// R8 = R5's verified global_load_lds GEMM K-loop (57.6us QKV, 0 conflicts,
// no spill) + R7's fused prologue (inline dtype detect, fused canon, fused
// transposes; 5 launches). R6/R7's global->VGPR->LDS staging is abandoned:
// the allocator spills the prefetch registers (WRITE_SIZE 419-439 MB scratch)
// under every bounds setting tried.
// ---------------------------------------------------------------------------

typedef __bf16 bf16_t;
typedef bf16_t bf16x8 __attribute__((ext_vector_type(8)));
typedef bf16_t bf16x4 __attribute__((ext_vector_type(4)));
typedef float  floatx4 __attribute__((ext_vector_type(4)));

#define SEQ_T   2048
#define NHEAD   16
#define HDIM    64
#define EMB     1024
#define WIN     256
#define SCALE_F 0.125f

// ---------------------------------------------------------------------------
// Wave-uniform dtype detect: all waves read the same 1 KB of hidden.
// bf16 -> low-16 exponent near 127 (~99% in [100,150]); fp32 -> ~20%.
// ---------------------------------------------------------------------------
__device__ __forceinline__ int detect_bf16(const uint4* __restrict__ det)
{
    const int lane = threadIdx.x & 63;
    const uint4 v = det[lane];
    int c = 0;
    #pragma unroll
    for (int e = 0; e < 4; ++e) {
        const unsigned int ex = ((&v.x)[e] >> 7) & 0xffu;
        c += (ex >= 100u && ex <= 150u) ? 1 : 0;
    }
    #pragma unroll
    for (int m = 32; m >= 1; m >>= 1) c += __shfl_xor(c, m, 64);
    return (c * 2 > 256) ? 1 : 0;
}

// ---------------------------------------------------------------------------
// canon_all: only does work when inputs are fp32 (flag==0).
// blocks 0..4095: hidden -> Hc; 4096..4098: b_attn; 4099: b_proj.
// ---------------------------------------------------------------------------
__global__ __launch_bounds__(256) void canon_all(
    const void* __restrict__ hidden, bf16_t* __restrict__ Hc,
    const void* __restrict__ ba, bf16_t* __restrict__ bba,
    const void* __restrict__ bp, bf16_t* __restrict__ bbp)
{
    if (detect_bf16((const uint4*)hidden)) return;
    const int blk = blockIdx.x;
    const float* src;
    bf16_t* dst;
    int base;
    if (blk < 4096)      { src = (const float*)hidden; dst = Hc;  base = blk * 1024; }
    else if (blk < 4099) { src = (const float*)ba;     dst = bba; base = (blk - 4096) * 1024; }
    else                 { src = (const float*)bp;     dst = bbp; base = 0; }
    const int i4 = base + threadIdx.x * 4;
    const float4 x = *(const float4*)(src + i4);
    bf16x4 v;
    v[0] = (bf16_t)x.x; v[1] = (bf16_t)x.y;
    v[2] = (bf16_t)x.z; v[3] = (bf16_t)x.w;
    *(bf16x4*)(dst + i4) = v;
}

// ---------------------------------------------------------------------------
// Both weight transposes in one launch. blocks 0..767: w_attn (N=3072);
// 768..1023: w_proj (N=1024). Wt[n][k] = (bf16)W[k][n].
// ---------------------------------------------------------------------------
__global__ __launch_bounds__(256) void transpose_both(
    const void* __restrict__ wA, bf16_t* __restrict__ WtA,
    const void* __restrict__ wP, bf16_t* __restrict__ WtP,
    const uint4* __restrict__ det)
{
    __shared__ __align__(16) bf16_t tile[64][68];
    const int f = detect_bf16(det);
    int id = blockIdx.x;
    const void* W; bf16_t* Wt; int N, bx, by;
    if (id < 768) { W = wA; Wt = WtA; N = 3072; bx = id % 48; by = id / 48; }
    else { id -= 768; W = wP; Wt = WtP; N = 1024; bx = id % 16; by = id / 16; }
    const int K = 1024;
    const int n0 = bx * 64;
    const int k0 = by * 64;
    const int tx = threadIdx.x & 15;
    const int ty = threadIdx.x >> 4;

    #pragma unroll
    for (int r = ty; r < 64; r += 16) {
        bf16x4 v;
        const size_t base = (size_t)(k0 + r) * N + n0 + tx * 4;
        if (f) {
            v = *(const bf16x4*)((const bf16_t*)W + base);
        } else {
            const float4 x = *(const float4*)((const float*)W + base);
            v[0] = (bf16_t)x.x; v[1] = (bf16_t)x.y;
            v[2] = (bf16_t)x.z; v[3] = (bf16_t)x.w;
        }
        *(bf16x4*)&tile[r][tx * 4] = v;
    }
    __syncthreads();
    #pragma unroll
    for (int r = ty; r < 64; r += 16) {
        bf16x4 v;
        v[0] = tile[tx * 4 + 0][r];
        v[1] = tile[tx * 4 + 1][r];
        v[2] = tile[tx * 4 + 2][r];
        v[3] = tile[tx * 4 + 3][r];
        *(bf16x4*)(Wt + (size_t)(n0 + r) * K + k0 + tx * 4) = v;
    }
}

// ---------------------------------------------------------------------------
// C[M][N] = A[M][K] @ Bt[N][K]^T + bias[N]   (bf16 in, fp32 accumulate)
// R5 structure (verified: 57.6us QKV, SQ_LDS_BANK_CONFLICT=0, no spill):
// BK=64 single-buffer global_load_lds staging, XOR swizzle in the per-lane
// GLOBAL source address (stored slot s of row r holds global chunk s^(r&7);
// LDS dest stays wave-uniform base + lane*16). Fragment reads hit all 32
// banks at 2 lanes/bank (free). Templated BNt: 128 for QKV, 64 for proj.
// ---------------------------------------------------------------------------
template<int BNt>
__global__ __launch_bounds__(256) void gemm_bt_bias(
    const bf16_t* __restrict__ Abf,   // used when flag==1 (bf16 input)
    const bf16_t* __restrict__ Aalt,  // used when flag==0 (canonicalized)
    const bf16_t* __restrict__ Bt,
    const bf16_t* __restrict__ biasbf,
    const bf16_t* __restrict__ biasalt,
    void* __restrict__ C,
    int M, int N, int K,
    int force_bf16, const uint4* __restrict__ det)
{
    constexpr int BMt = 128;
    constexpr int NF  = BNt / 32;     // n-frags per wave (wave tile = 64 x BNt/2)
    __shared__ __align__(16) bf16_t As[BMt * 64];   // 16 KB
    __shared__ __align__(16) bf16_t Bs[BNt * 64];   // 16 or 8 KB

    const int flag = detect_bf16(det);
    const bf16_t* A    = flag ? Abf    : Aalt;
    const bf16_t* bias = flag ? biasbf : biasalt;
    const int obf = force_bf16 | flag;

    const int tid  = threadIdx.x;
    const int wave = tid >> 6;
    const int lane = tid & 63;
    const int quad = lane >> 4;
    const int n16  = lane & 15;
    const int m0 = blockIdx.y * BMt;
    const int n0 = blockIdx.x * BNt;
    const int wm = (wave >> 1) * 64;
    const int wn = (wave & 1) * (BNt / 2);

    floatx4 acc[4][NF] = {};

    // staging: each global_load_lds moves 8 rows x 64 cols (128 B/row);
    // lane L covers row (L>>3), stored slot (L&7) <- global chunk (L&7)^(L>>3)
    const int lr = lane >> 3;
    const int g8 = ((lane & 7) ^ lr) * 8;

    for (int k0 = 0; k0 < K; k0 += 64) {
        #pragma unroll
        for (int t = 0; t < BMt / 32; ++t) {
            const int row0 = wave * (BMt / 4) + t * 8;
            const bf16_t* ga = A + (size_t)(m0 + row0 + lr) * K + k0 + g8;
            __builtin_amdgcn_global_load_lds(
                (const __attribute__((address_space(1))) void*)ga,
                (__attribute__((address_space(3))) void*)(As + row0 * 64),
                16, 0, 0);
        }
        #pragma unroll
        for (int t = 0; t < BNt / 32; ++t) {
            const int row0 = wave * (BNt / 4) + t * 8;
            const bf16_t* gb = Bt + (size_t)(n0 + row0 + lr) * K + k0 + g8;
            __builtin_amdgcn_global_load_lds(
                (const __attribute__((address_space(1))) void*)gb,
                (__attribute__((address_space(3))) void*)(Bs + row0 * 64),
                16, 0, 0);
        }
        __syncthreads();

        // fragment reads: row = w?+ff*16+n16 (row&7 == n16&7), want global
        // chunk (4s+quad) -> read slot (4s+quad)^(n16&7)
        #pragma unroll
        for (int s = 0; s < 2; ++s) {
            const int ch = (((4 * s + quad) ^ (n16 & 7)) * 8);
            const bf16_t* pa = As + (wm + n16) * 64 + ch;
            const bf16_t* pb = Bs + (wn + n16) * 64 + ch;
            bf16x8 af[4], bfr[NF];
            #pragma unroll
            for (int ff = 0; ff < 4; ++ff)
                af[ff] = *(const bf16x8*)(pa + ff * 16 * 64);
            #pragma unroll
            for (int ff = 0; ff < NF; ++ff)
                bfr[ff] = *(const bf16x8*)(pb + ff * 16 * 64);
            #pragma unroll
            for (int mf = 0; mf < 4; ++mf)
                #pragma unroll
                for (int nf = 0; nf < NF; ++nf)
                    acc[mf][nf] = __builtin_amdgcn_mfma_f32_16x16x32_bf16(
                        af[mf], bfr[nf], acc[mf][nf], 0, 0, 0);
        }
        __syncthreads();
    }

    const int col   = n0 + wn + n16;
    const int rbase = m0 + wm + quad * 4;
    #pragma unroll
    for (int nf = 0; nf < NF; ++nf) {
        const float bv = (float)bias[col + nf * 16];
        #pragma unroll
        for (int mf = 0; mf < 4; ++mf) {
            #pragma unroll
            for (int r = 0; r < 4; ++r) {
                const size_t idx =
                    (size_t)(rbase + mf * 16 + r) * N + col + nf * 16;
                const float val = acc[mf][nf][r] + bv;
                if (obf) ((bf16_t*)C)[idx] = (bf16_t)val;
                else     ((float*)C)[idx]  = val;
            }
        }
    }
}

// ---------------------------------------------------------------------------
// MFMA flash attention (verified R3, unchanged). Block = (b,h,64-query tile).
// ---------------------------------------------------------------------------
#define CW   160
#define VT_S 168
#define P_S  168

__global__ __launch_bounds__(256) void attn_mfma(
    const bf16_t* __restrict__ qkv,
    bf16_t* __restrict__ attn_out)
{
    __shared__ __align__(16) bf16_t Ks[CW * 64];       // 20480 B
    __shared__ __align__(16) bf16_t Vt[64 * VT_S];     // 21504 B
    __shared__ __align__(16) bf16_t Pst[4][16 * P_S];  // 21504 B

    const int tid  = threadIdx.x;
    const int wave = tid >> 6;
    const int lane = tid & 63;
    const int quad = lane >> 4;
    const int n16  = lane & 15;

    const int i0 = blockIdx.x * 64;
    const int h  = blockIdx.y;
    const int b  = blockIdx.z;
    const size_t rowbase = (size_t)b * SEQ_T;
    const int kbase  = i0 - 256;
    const int iw     = 16 * wave;
    const int climit = 256 - i0;

    const bf16_t* Qg = qkv + (rowbase + i0 + iw + n16) * (3 * EMB) + h * HDIM;
    bf16x8 qf[2];
    qf[0] = *(const bf16x8*)(Qg + quad * 8);
    qf[1] = *(const bf16x8*)(Qg + 32 + quad * 8);

    floatx4 Oac[4] = {};
    float m_run[4], l_run[4];
    #pragma unroll
    for (int rr = 0; rr < 4; ++rr) { m_run[rr] = -3.0e38f; l_run[rr] = 0.f; }

    for (int hc = 0; hc < 2; ++hc) {
        const int cbase = hc * CW;

        bf16x8 vreg[5];
        #pragma unroll
        for (int t = 0; t < 5; ++t) {
            const int idx = tid + 256 * t;
            const int lc  = idx >> 3;
            const int d0  = (idx & 7) * 8;
            int j = kbase + cbase + lc; if (j < 0) j = 0;
            vreg[t] = *(const bf16x8*)(qkv + (rowbase + j) * (3 * EMB)
                                       + 2 * EMB + h * HDIM + d0);
        }

        __syncthreads();

        #pragma unroll
        for (int t = 0; t < 5; ++t) {
            const int lc0 = wave * 40 + t * 8;
            const int lcL = lc0 + (lane >> 3);
            int j = kbase + cbase + lcL; if (j < 0) j = 0;
            const int g = (lane & 7) ^ (lcL & 7);
            const bf16_t* src = qkv + (rowbase + j) * (3 * EMB)
                                + EMB + h * HDIM + g * 8;
            __builtin_amdgcn_global_load_lds(
                (const __attribute__((address_space(1))) void*)src,
                (__attribute__((address_space(3))) void*)(Ks + lc0 * 64),
                16, 0, 0);
        }

        #pragma unroll
        for (int t = 0; t < 5; ++t) {
            const int idx = tid + 256 * t;
            const int lc  = idx >> 3;
            const int d0  = (idx & 7) * 8;
            #pragma unroll
            for (int e = 0; e < 8; ++e)
                Vt[(d0 + e) * VT_S + lc] = vreg[t][e];
        }

        __syncthreads();

        floatx4 sc[10];
        #pragma unroll
        for (int tt = 0; tt < 10; ++tt) {
            sc[tt] = (floatx4){0.f, 0.f, 0.f, 0.f};
            #pragma unroll
            for (int s2 = 0; s2 < 2; ++s2) {
                const int lc = 16 * tt + n16;
                const int ch = (4 * s2 + quad) ^ (lc & 7);
                const bf16x8 kf = *(const bf16x8*)(Ks + lc * 64 + ch * 8);
                sc[tt] = __builtin_amdgcn_mfma_f32_16x16x32_bf16(
                    qf[s2], kf, sc[tt], 0, 0, 0);
            }
        }

        #pragma unroll
        for (int tt = 0; tt < 10; ++tt) {
            const int c  = cbase + 16 * tt + n16;
            const int cw = c - iw;
            #pragma unroll
            for (int rr = 0; rr < 4; ++rr) {
                const int r = quad * 4 + rr;
                const bool valid = (cw > r) && (cw <= r + 256) && (c >= climit);
                sc[tt][rr] = valid ? sc[tt][rr] * SCALE_F : -3.0e38f;
            }
        }

        float cm[4];
        #pragma unroll
        for (int rr = 0; rr < 4; ++rr) {
            cm[rr] = -3.0e38f;
            #pragma unroll
            for (int tt = 0; tt < 10; ++tt) cm[rr] = fmaxf(cm[rr], sc[tt][rr]);
            #pragma unroll
            for (int m = 8; m >= 1; m >>= 1)
                cm[rr] = fmaxf(cm[rr], __shfl_xor(cm[rr], m, 64));
        }

        #pragma unroll
        for (int rr = 0; rr < 4; ++rr) {
            const float mnew  = fmaxf(m_run[rr], cm[rr]);
            const float alpha = __expf(m_run[rr] - mnew);
            m_run[rr] = mnew;
            l_run[rr] *= alpha;
            #pragma unroll
            for (int nt = 0; nt < 4; ++nt) Oac[nt][rr] *= alpha;
        }

        float psum[4] = {0.f, 0.f, 0.f, 0.f};
        #pragma unroll
        for (int tt = 0; tt < 10; ++tt) {
            #pragma unroll
            for (int rr = 0; rr < 4; ++rr) {
                const float s = sc[tt][rr];
                const float e = (s > -1.0e38f) ? __expf(s - m_run[rr]) : 0.f;
                psum[rr] += e;
                Pst[wave][(quad * 4 + rr) * P_S + 16 * tt + n16] = (bf16_t)e;
            }
        }
        #pragma unroll
        for (int rr = 0; rr < 4; ++rr) {
            #pragma unroll
            for (int m = 8; m >= 1; m >>= 1)
                psum[rr] += __shfl_xor(psum[rr], m, 64);
            l_run[rr] += psum[rr];
        }

        __syncthreads();

        #pragma unroll
        for (int ks = 0; ks < 5; ++ks) {
            const bf16x8 paf = *(const bf16x8*)(
                &Pst[wave][n16 * P_S + ks * 32 + quad * 8]);
            #pragma unroll
            for (int nt = 0; nt < 4; ++nt) {
                const bf16x8 vbf = *(const bf16x8*)(
                    Vt + (nt * 16 + n16) * VT_S + ks * 32 + quad * 8);
                Oac[nt] = __builtin_amdgcn_mfma_f32_16x16x32_bf16(
                    paf, vbf, Oac[nt], 0, 0, 0);
            }
        }
    }

    #pragma unroll
    for (int rr = 0; rr < 4; ++rr) {
        const float rden = 1.0f / l_run[rr];
        const size_t row = rowbase + i0 + iw + quad * 4 + rr;
        #pragma unroll
        for (int nt = 0; nt < 4; ++nt) {
            attn_out[row * EMB + h * HDIM + nt * 16 + n16] =
                (bf16_t)(Oac[nt][rr] * rden);
        }
    }
}

// ---------------------------------------------------------------------------
extern "C" void kernel_launch(void* const* d_in, const int* in_sizes, int n_in,
                              void* d_out, int out_size, void* d_ws, size_t ws_size,
                              hipStream_t stream)
{
    const void* hidden = d_in[0];
    const void* w_attn = d_in[1];
    const void* b_attn = d_in[2];
    const void* w_proj = d_in[3];
    const void* b_proj = d_in[4];

    char* ws = (char*)d_ws;
    bf16_t* Wt_attn = (bf16_t*)(ws);                       // [3072][1024]
    bf16_t* Wt_proj = (bf16_t*)(ws + (6u << 20));          // [1024][1024]
    bf16_t* qkv     = (bf16_t*)(ws + (8u << 20));          // [4096][3072]
    bf16_t* attn_o  = (bf16_t*)(ws + (32u << 20));         // [4096][1024]
    bf16_t* Hc      = (bf16_t*)(ws + (40u << 20));         // [4096][1024]
    bf16_t* bb_attn = (bf16_t*)(ws + (48u << 20));
    bf16_t* bb_proj = (bf16_t*)(ws + (48u << 20) + 8192);

    const uint4* det = (const uint4*)hidden;

    canon_all<<<4100, 256, 0, stream>>>(hidden, Hc, b_attn, bb_attn,
                                        b_proj, bb_proj);

    transpose_both<<<1024, 256, 0, stream>>>(w_attn, Wt_attn,
                                             w_proj, Wt_proj, det);

    gemm_bt_bias<128><<<dim3(3072 / 128, 4096 / 128), 256, 0, stream>>>(
        (const bf16_t*)hidden, Hc, Wt_attn,
        (const bf16_t*)b_attn, bb_attn, qkv, 4096, 3072, 1024, 1, det);

    attn_mfma<<<dim3(SEQ_T / 64, NHEAD, 2), 256, 0, stream>>>(qkv, attn_o);

    gemm_bt_bias<64><<<dim3(1024 / 64, 4096 / 128), 256, 0, stream>>>(
        attn_o, attn_o, Wt_proj,
        (const bf16_t*)b_proj, bb_proj, (void*)d_out, 4096, 1024, 1024, 0, det);
}

// Round 9
// 172.104 us; speedup vs baseline: 1.7853x; 1.0104x over previous
//
#include <hip/hip_runtime.h>

// ---------------------------------------------------------------------------
// MaskedMultiHeadAttention: B=2, T=2048, E=1024, H=16, D=64, WINDOW=256
//
// R9: QKV GEMM gets 64x128 wave tiles (block 128x256, acc[4][8]) to raise
// FLOP/LDS-byte from 32 -> 43.7 (LDS pipe was co-limiting at 64x64) and to
// double MFMA-per-barrier. Staging stays global_load_lds (no staging VGPRs,
// no R6/R7 spill trap). Prologue fused to ONE kernel. 4 launches total.
// ---------------------------------------------------------------------------

typedef __bf16 bf16_t;
typedef bf16_t bf16x8 __attribute__((ext_vector_type(8)));
typedef bf16_t bf16x4 __attribute__((ext_vector_type(4)));
typedef float  floatx4 __attribute__((ext_vector_type(4)));

#define SEQ_T   2048
#define NHEAD   16
#define HDIM    64
#define EMB     1024
#define WIN     256
#define SCALE_F 0.125f

// ---------------------------------------------------------------------------
// Wave-uniform dtype detect: all waves read the same 1 KB of hidden.
// bf16 -> low-16 exponent near 127 (~99% in [100,150]); fp32 -> ~20%.
// ---------------------------------------------------------------------------
__device__ __forceinline__ int detect_bf16(const uint4* __restrict__ det)
{
    const int lane = threadIdx.x & 63;
    const uint4 v = det[lane];
    int c = 0;
    #pragma unroll
    for (int e = 0; e < 4; ++e) {
        const unsigned int ex = ((&v.x)[e] >> 7) & 0xffu;
        c += (ex >= 100u && ex <= 150u) ? 1 : 0;
    }
    #pragma unroll
    for (int m = 32; m >= 1; m >>= 1) c += __shfl_xor(c, m, 64);
    return (c * 2 > 256) ? 1 : 0;
}

// ---------------------------------------------------------------------------
// Fused prologue (one launch):
//   blocks 0..4095    : hidden -> Hc (fp32 mode only; early-exit when bf16)
//   blocks 4096..4098 : b_attn -> bba (fp32 mode only)
//   block  4099       : b_proj -> bbp (fp32 mode only)
//   blocks 4100..4867 : transpose w_attn (N=3072)
//   blocks 4868..5123 : transpose w_proj (N=1024)
// ---------------------------------------------------------------------------
__global__ __launch_bounds__(256) void prologue(
    const void* __restrict__ hidden, bf16_t* __restrict__ Hc,
    const void* __restrict__ ba, bf16_t* __restrict__ bba,
    const void* __restrict__ bp, bf16_t* __restrict__ bbp,
    const void* __restrict__ wA, bf16_t* __restrict__ WtA,
    const void* __restrict__ wP, bf16_t* __restrict__ WtP)
{
    __shared__ __align__(16) bf16_t tile[64][68];
    const int f = detect_bf16((const uint4*)hidden);
    const int blk = blockIdx.x;

    if (blk < 4100) {                       // canonicalize path
        if (f) return;                      // bf16 inputs: nothing to do
        const float* src;
        bf16_t* dst;
        int base;
        if (blk < 4096)      { src = (const float*)hidden; dst = Hc;  base = blk * 1024; }
        else if (blk < 4099) { src = (const float*)ba;     dst = bba; base = (blk - 4096) * 1024; }
        else                 { src = (const float*)bp;     dst = bbp; base = 0; }
        const int i4 = base + threadIdx.x * 4;
        const float4 x = *(const float4*)(src + i4);
        bf16x4 v;
        v[0] = (bf16_t)x.x; v[1] = (bf16_t)x.y;
        v[2] = (bf16_t)x.z; v[3] = (bf16_t)x.w;
        *(bf16x4*)(dst + i4) = v;
        return;
    }

    // transpose path
    int id = blk - 4100;
    const void* W; bf16_t* Wt; int N, bx, by;
    if (id < 768) { W = wA; Wt = WtA; N = 3072; bx = id % 48; by = id / 48; }
    else { id -= 768; W = wP; Wt = WtP; N = 1024; bx = id % 16; by = id / 16; }
    const int K = 1024;
    const int n0 = bx * 64;
    const int k0 = by * 64;
    const int tx = threadIdx.x & 15;
    const int ty = threadIdx.x >> 4;

    #pragma unroll
    for (int r = ty; r < 64; r += 16) {
        bf16x4 v;
        const size_t base = (size_t)(k0 + r) * N + n0 + tx * 4;
        if (f) {
            v = *(const bf16x4*)((const bf16_t*)W + base);
        } else {
            const float4 x = *(const float4*)((const float*)W + base);
            v[0] = (bf16_t)x.x; v[1] = (bf16_t)x.y;
            v[2] = (bf16_t)x.z; v[3] = (bf16_t)x.w;
        }
        *(bf16x4*)&tile[r][tx * 4] = v;
    }
    __syncthreads();
    #pragma unroll
    for (int r = ty; r < 64; r += 16) {
        bf16x4 v;
        v[0] = tile[tx * 4 + 0][r];
        v[1] = tile[tx * 4 + 1][r];
        v[2] = tile[tx * 4 + 2][r];
        v[3] = tile[tx * 4 + 3][r];
        *(bf16x4*)(Wt + (size_t)(n0 + r) * K + k0 + tx * 4) = v;
    }
}

// ---------------------------------------------------------------------------
// C[M][N] = A[M][K] @ Bt[N][K]^T + bias[N]   (bf16 in, fp32 accumulate)
// R5/R8-verified K-loop: BK=64 single-buffer global_load_lds staging, XOR
// source-address swizzle (stored slot s of row r = global chunk s^(r&7);
// LDS dest stays wave-uniform + lane*16) -> conflict-free fragment reads.
// Wave grid 2x2; wave tile = 64 x (BNt/2). BNt=256 -> 64x128 wave tiles:
// 43.7 FLOP/LDS-byte (vs 32 at 64x64) and 64 MFMA per barrier.
// ---------------------------------------------------------------------------
template<int BNt>
__global__ __launch_bounds__(256, 2) void gemm_bt_bias(
    const bf16_t* __restrict__ Abf,   // used when flag==1 (bf16 input)
    const bf16_t* __restrict__ Aalt,  // used when flag==0 (canonicalized)
    const bf16_t* __restrict__ Bt,
    const bf16_t* __restrict__ biasbf,
    const bf16_t* __restrict__ biasalt,
    void* __restrict__ C,
    int M, int N, int K,
    int force_bf16, const uint4* __restrict__ det)
{
    constexpr int BMt = 128;
    constexpr int NF  = BNt / 32;     // n-frags per wave (wave tile = 64 x BNt/2)
    __shared__ __align__(16) bf16_t As[BMt * 64];   // 16 KB
    __shared__ __align__(16) bf16_t Bs[BNt * 64];   // 32/16/8 KB

    const int flag = detect_bf16(det);
    const bf16_t* A    = flag ? Abf    : Aalt;
    const bf16_t* bias = flag ? biasbf : biasalt;
    const int obf = force_bf16 | flag;

    const int tid  = threadIdx.x;
    const int wave = tid >> 6;
    const int lane = tid & 63;
    const int quad = lane >> 4;
    const int n16  = lane & 15;
    const int m0 = blockIdx.y * BMt;
    const int n0 = blockIdx.x * BNt;
    const int wm = (wave >> 1) * 64;
    const int wn = (wave & 1) * (BNt / 2);

    floatx4 acc[4][NF] = {};

    // staging: each global_load_lds moves 8 rows x 64 cols (128 B/row);
    // lane L covers row (L>>3), stored slot (L&7) <- global chunk (L&7)^(L>>3)
    const int lr = lane >> 3;
    const int g8 = ((lane & 7) ^ lr) * 8;

    for (int k0 = 0; k0 < K; k0 += 64) {
        #pragma unroll
        for (int t = 0; t < BMt / 32; ++t) {
            const int row0 = wave * (BMt / 4) + t * 8;
            const bf16_t* ga = A + (size_t)(m0 + row0 + lr) * K + k0 + g8;
            __builtin_amdgcn_global_load_lds(
                (const __attribute__((address_space(1))) void*)ga,
                (__attribute__((address_space(3))) void*)(As + row0 * 64),
                16, 0, 0);
        }
        #pragma unroll
        for (int t = 0; t < BNt / 32; ++t) {
            const int row0 = wave * (BNt / 4) + t * 8;
            const bf16_t* gb = Bt + (size_t)(n0 + row0 + lr) * K + k0 + g8;
            __builtin_amdgcn_global_load_lds(
                (const __attribute__((address_space(1))) void*)gb,
                (__attribute__((address_space(3))) void*)(Bs + row0 * 64),
                16, 0, 0);
        }
        __syncthreads();

        // fragment reads: row = w?+ff*16+n16 (row&7 == n16&7), want global
        // chunk (4s+quad) -> read slot (4s+quad)^(n16&7)
        #pragma unroll
        for (int s = 0; s < 2; ++s) {
            const int ch = (((4 * s + quad) ^ (n16 & 7)) * 8);
            const bf16_t* pa = As + (wm + n16) * 64 + ch;
            const bf16_t* pb = Bs + (wn + n16) * 64 + ch;
            bf16x8 af[4], bfr[NF];
            #pragma unroll
            for (int ff = 0; ff < 4; ++ff)
                af[ff] = *(const bf16x8*)(pa + ff * 16 * 64);
            #pragma unroll
            for (int ff = 0; ff < NF; ++ff)
                bfr[ff] = *(const bf16x8*)(pb + ff * 16 * 64);
            #pragma unroll
            for (int mf = 0; mf < 4; ++mf)
                #pragma unroll
                for (int nf = 0; nf < NF; ++nf)
                    acc[mf][nf] = __builtin_amdgcn_mfma_f32_16x16x32_bf16(
                        af[mf], bfr[nf], acc[mf][nf], 0, 0, 0);
        }
        __syncthreads();
    }

    const int col   = n0 + wn + n16;
    const int rbase = m0 + wm + quad * 4;
    #pragma unroll
    for (int nf = 0; nf < NF; ++nf) {
        const float bv = (float)bias[col + nf * 16];
        #pragma unroll
        for (int mf = 0; mf < 4; ++mf) {
            #pragma unroll
            for (int r = 0; r < 4; ++r) {
                const size_t idx =
                    (size_t)(rbase + mf * 16 + r) * N + col + nf * 16;
                const float val = acc[mf][nf][r] + bv;
                if (obf) ((bf16_t*)C)[idx] = (bf16_t)val;
                else     ((float*)C)[idx]  = val;
            }
        }
    }
}

// ---------------------------------------------------------------------------
// MFMA flash attention (verified R3, unchanged). Block = (b,h,64-query tile).
// ---------------------------------------------------------------------------
#define CW   160
#define VT_S 168
#define P_S  168

__global__ __launch_bounds__(256) void attn_mfma(
    const bf16_t* __restrict__ qkv,
    bf16_t* __restrict__ attn_out)
{
    __shared__ __align__(16) bf16_t Ks[CW * 64];       // 20480 B
    __shared__ __align__(16) bf16_t Vt[64 * VT_S];     // 21504 B
    __shared__ __align__(16) bf16_t Pst[4][16 * P_S];  // 21504 B

    const int tid  = threadIdx.x;
    const int wave = tid >> 6;
    const int lane = tid & 63;
    const int quad = lane >> 4;
    const int n16  = lane & 15;

    const int i0 = blockIdx.x * 64;
    const int h  = blockIdx.y;
    const int b  = blockIdx.z;
    const size_t rowbase = (size_t)b * SEQ_T;
    const int kbase  = i0 - 256;
    const int iw     = 16 * wave;
    const int climit = 256 - i0;

    const bf16_t* Qg = qkv + (rowbase + i0 + iw + n16) * (3 * EMB) + h * HDIM;
    bf16x8 qf[2];
    qf[0] = *(const bf16x8*)(Qg + quad * 8);
    qf[1] = *(const bf16x8*)(Qg + 32 + quad * 8);

    floatx4 Oac[4] = {};
    float m_run[4], l_run[4];
    #pragma unroll
    for (int rr = 0; rr < 4; ++rr) { m_run[rr] = -3.0e38f; l_run[rr] = 0.f; }

    for (int hc = 0; hc < 2; ++hc) {
        const int cbase = hc * CW;

        bf16x8 vreg[5];
        #pragma unroll
        for (int t = 0; t < 5; ++t) {
            const int idx = tid + 256 * t;
            const int lc  = idx >> 3;
            const int d0  = (idx & 7) * 8;
            int j = kbase + cbase + lc; if (j < 0) j = 0;
            vreg[t] = *(const bf16x8*)(qkv + (rowbase + j) * (3 * EMB)
                                       + 2 * EMB + h * HDIM + d0);
        }

        __syncthreads();

        #pragma unroll
        for (int t = 0; t < 5; ++t) {
            const int lc0 = wave * 40 + t * 8;
            const int lcL = lc0 + (lane >> 3);
            int j = kbase + cbase + lcL; if (j < 0) j = 0;
            const int g = (lane & 7) ^ (lcL & 7);
            const bf16_t* src = qkv + (rowbase + j) * (3 * EMB)
                                + EMB + h * HDIM + g * 8;
            __builtin_amdgcn_global_load_lds(
                (const __attribute__((address_space(1))) void*)src,
                (__attribute__((address_space(3))) void*)(Ks + lc0 * 64),
                16, 0, 0);
        }

        #pragma unroll
        for (int t = 0; t < 5; ++t) {
            const int idx = tid + 256 * t;
            const int lc  = idx >> 3;
            const int d0  = (idx & 7) * 8;
            #pragma unroll
            for (int e = 0; e < 8; ++e)
                Vt[(d0 + e) * VT_S + lc] = vreg[t][e];
        }

        __syncthreads();

        floatx4 sc[10];
        #pragma unroll
        for (int tt = 0; tt < 10; ++tt) {
            sc[tt] = (floatx4){0.f, 0.f, 0.f, 0.f};
            #pragma unroll
            for (int s2 = 0; s2 < 2; ++s2) {
                const int lc = 16 * tt + n16;
                const int ch = (4 * s2 + quad) ^ (lc & 7);
                const bf16x8 kf = *(const bf16x8*)(Ks + lc * 64 + ch * 8);
                sc[tt] = __builtin_amdgcn_mfma_f32_16x16x32_bf16(
                    qf[s2], kf, sc[tt], 0, 0, 0);
            }
        }

        #pragma unroll
        for (int tt = 0; tt < 10; ++tt) {
            const int c  = cbase + 16 * tt + n16;
            const int cw = c - iw;
            #pragma unroll
            for (int rr = 0; rr < 4; ++rr) {
                const int r = quad * 4 + rr;
                const bool valid = (cw > r) && (cw <= r + 256) && (c >= climit);
                sc[tt][rr] = valid ? sc[tt][rr] * SCALE_F : -3.0e38f;
            }
        }

        float cm[4];
        #pragma unroll
        for (int rr = 0; rr < 4; ++rr) {
            cm[rr] = -3.0e38f;
            #pragma unroll
            for (int tt = 0; tt < 10; ++tt) cm[rr] = fmaxf(cm[rr], sc[tt][rr]);
            #pragma unroll
            for (int m = 8; m >= 1; m >>= 1)
                cm[rr] = fmaxf(cm[rr], __shfl_xor(cm[rr], m, 64));
        }

        #pragma unroll
        for (int rr = 0; rr < 4; ++rr) {
            const float mnew  = fmaxf(m_run[rr], cm[rr]);
            const float alpha = __expf(m_run[rr] - mnew);
            m_run[rr] = mnew;
            l_run[rr] *= alpha;
            #pragma unroll
            for (int nt = 0; nt < 4; ++nt) Oac[nt][rr] *= alpha;
        }

        float psum[4] = {0.f, 0.f, 0.f, 0.f};
        #pragma unroll
        for (int tt = 0; tt < 10; ++tt) {
            #pragma unroll
            for (int rr = 0; rr < 4; ++rr) {
                const float s = sc[tt][rr];
                const float e = (s > -1.0e38f) ? __expf(s - m_run[rr]) : 0.f;
                psum[rr] += e;
                Pst[wave][(quad * 4 + rr) * P_S + 16 * tt + n16] = (bf16_t)e;
            }
        }
        #pragma unroll
        for (int rr = 0; rr < 4; ++rr) {
            #pragma unroll
            for (int m = 8; m >= 1; m >>= 1)
                psum[rr] += __shfl_xor(psum[rr], m, 64);
            l_run[rr] += psum[rr];
        }

        __syncthreads();

        #pragma unroll
        for (int ks = 0; ks < 5; ++ks) {
            const bf16x8 paf = *(const bf16x8*)(
                &Pst[wave][n16 * P_S + ks * 32 + quad * 8]);
            #pragma unroll
            for (int nt = 0; nt < 4; ++nt) {
                const bf16x8 vbf = *(const bf16x8*)(
                    Vt + (nt * 16 + n16) * VT_S + ks * 32 + quad * 8);
                Oac[nt] = __builtin_amdgcn_mfma_f32_16x16x32_bf16(
                    paf, vbf, Oac[nt], 0, 0, 0);
            }
        }
    }

    #pragma unroll
    for (int rr = 0; rr < 4; ++rr) {
        const float rden = 1.0f / l_run[rr];
        const size_t row = rowbase + i0 + iw + quad * 4 + rr;
        #pragma unroll
        for (int nt = 0; nt < 4; ++nt) {
            attn_out[row * EMB + h * HDIM + nt * 16 + n16] =
                (bf16_t)(Oac[nt][rr] * rden);
        }
    }
}

// ---------------------------------------------------------------------------
extern "C" void kernel_launch(void* const* d_in, const int* in_sizes, int n_in,
                              void* d_out, int out_size, void* d_ws, size_t ws_size,
                              hipStream_t stream)
{
    const void* hidden = d_in[0];
    const void* w_attn = d_in[1];
    const void* b_attn = d_in[2];
    const void* w_proj = d_in[3];
    const void* b_proj = d_in[4];

    char* ws = (char*)d_ws;
    bf16_t* Wt_attn = (bf16_t*)(ws);                       // [3072][1024]
    bf16_t* Wt_proj = (bf16_t*)(ws + (6u << 20));          // [1024][1024]
    bf16_t* qkv     = (bf16_t*)(ws + (8u << 20));          // [4096][3072]
    bf16_t* attn_o  = (bf16_t*)(ws + (32u << 20));         // [4096][1024]
    bf16_t* Hc      = (bf16_t*)(ws + (40u << 20));         // [4096][1024]
    bf16_t* bb_attn = (bf16_t*)(ws + (48u << 20));
    bf16_t* bb_proj = (bf16_t*)(ws + (48u << 20) + 8192);

    const uint4* det = (const uint4*)hidden;

    prologue<<<5124, 256, 0, stream>>>(hidden, Hc, b_attn, bb_attn,
                                       b_proj, bb_proj,
                                       w_attn, Wt_attn, w_proj, Wt_proj);

    gemm_bt_bias<256><<<dim3(3072 / 256, 4096 / 128), 256, 0, stream>>>(
        (const bf16_t*)hidden, Hc, Wt_attn,
        (const bf16_t*)b_attn, bb_attn, qkv, 4096, 3072, 1024, 1, det);

    attn_mfma<<<dim3(SEQ_T / 64, NHEAD, 2), 256, 0, stream>>>(qkv, attn_o);

    gemm_bt_bias<64><<<dim3(1024 / 64, 4096 / 128), 256, 0, stream>>>(
        attn_o, attn_o, Wt_proj,
        (const bf16_t*)b_proj, bb_proj, (void*)d_out, 4096, 1024, 1024, 0, det);
}

// Round 10
// 168.498 us; speedup vs baseline: 1.8235x; 1.0214x over previous
//
#include <hip/hip_runtime.h>

// ---------------------------------------------------------------------------
// MaskedMultiHeadAttention: B=2, T=2048, E=1024, H=16, D=64, WINDOW=256
//
// R10: (1) proj GEMM BK=128 (8 K-iters, 48KB LDS, 3 blocks/CU, 1 round);
//      (2) attention 4x80-key chunks (36KB LDS -> 4 blocks/CU -> 1024 blocks
//          = 1 round) with V-reg and K-lds prefetch hidden under compute.
// QKV GEMM (BNt=256, BK=64) and fused prologue unchanged from R9.
// ---------------------------------------------------------------------------

typedef __bf16 bf16_t;
typedef bf16_t bf16x8 __attribute__((ext_vector_type(8)));
typedef bf16_t bf16x4 __attribute__((ext_vector_type(4)));
typedef float  floatx4 __attribute__((ext_vector_type(4)));

#define SEQ_T   2048
#define NHEAD   16
#define HDIM    64
#define EMB     1024
#define WIN     256
#define SCALE_F 0.125f

// ---------------------------------------------------------------------------
// Wave-uniform dtype detect: all waves read the same 1 KB of hidden.
// ---------------------------------------------------------------------------
__device__ __forceinline__ int detect_bf16(const uint4* __restrict__ det)
{
    const int lane = threadIdx.x & 63;
    const uint4 v = det[lane];
    int c = 0;
    #pragma unroll
    for (int e = 0; e < 4; ++e) {
        const unsigned int ex = ((&v.x)[e] >> 7) & 0xffu;
        c += (ex >= 100u && ex <= 150u) ? 1 : 0;
    }
    #pragma unroll
    for (int m = 32; m >= 1; m >>= 1) c += __shfl_xor(c, m, 64);
    return (c * 2 > 256) ? 1 : 0;
}

// ---------------------------------------------------------------------------
// Fused prologue (one launch): canon (fp32 mode only) + both transposes.
// ---------------------------------------------------------------------------
__global__ __launch_bounds__(256) void prologue(
    const void* __restrict__ hidden, bf16_t* __restrict__ Hc,
    const void* __restrict__ ba, bf16_t* __restrict__ bba,
    const void* __restrict__ bp, bf16_t* __restrict__ bbp,
    const void* __restrict__ wA, bf16_t* __restrict__ WtA,
    const void* __restrict__ wP, bf16_t* __restrict__ WtP)
{
    __shared__ __align__(16) bf16_t tile[64][68];
    const int f = detect_bf16((const uint4*)hidden);
    const int blk = blockIdx.x;

    if (blk < 4100) {                       // canonicalize path
        if (f) return;
        const float* src;
        bf16_t* dst;
        int base;
        if (blk < 4096)      { src = (const float*)hidden; dst = Hc;  base = blk * 1024; }
        else if (blk < 4099) { src = (const float*)ba;     dst = bba; base = (blk - 4096) * 1024; }
        else                 { src = (const float*)bp;     dst = bbp; base = 0; }
        const int i4 = base + threadIdx.x * 4;
        const float4 x = *(const float4*)(src + i4);
        bf16x4 v;
        v[0] = (bf16_t)x.x; v[1] = (bf16_t)x.y;
        v[2] = (bf16_t)x.z; v[3] = (bf16_t)x.w;
        *(bf16x4*)(dst + i4) = v;
        return;
    }

    int id = blk - 4100;
    const void* W; bf16_t* Wt; int N, bx, by;
    if (id < 768) { W = wA; Wt = WtA; N = 3072; bx = id % 48; by = id / 48; }
    else { id -= 768; W = wP; Wt = WtP; N = 1024; bx = id % 16; by = id / 16; }
    const int K = 1024;
    const int n0 = bx * 64;
    const int k0 = by * 64;
    const int tx = threadIdx.x & 15;
    const int ty = threadIdx.x >> 4;

    #pragma unroll
    for (int r = ty; r < 64; r += 16) {
        bf16x4 v;
        const size_t base = (size_t)(k0 + r) * N + n0 + tx * 4;
        if (f) {
            v = *(const bf16x4*)((const bf16_t*)W + base);
        } else {
            const float4 x = *(const float4*)((const float*)W + base);
            v[0] = (bf16_t)x.x; v[1] = (bf16_t)x.y;
            v[2] = (bf16_t)x.z; v[3] = (bf16_t)x.w;
        }
        *(bf16x4*)&tile[r][tx * 4] = v;
    }
    __syncthreads();
    #pragma unroll
    for (int r = ty; r < 64; r += 16) {
        bf16x4 v;
        v[0] = tile[tx * 4 + 0][r];
        v[1] = tile[tx * 4 + 1][r];
        v[2] = tile[tx * 4 + 2][r];
        v[3] = tile[tx * 4 + 3][r];
        *(bf16x4*)(Wt + (size_t)(n0 + r) * K + k0 + tx * 4) = v;
    }
}

// ---------------------------------------------------------------------------
// C[M][N] = A[M][K] @ Bt[N][K]^T + bias[N]   (bf16 in, fp32 accumulate)
// Verified K-loop: single-buffer global_load_lds + XOR source-address swizzle
// (stored slot s of row r holds global chunk s ^ (r & CM); LDS dest stays
// wave-uniform + lane*16) -> conflict-free fragment reads.
// Template: BNt (block N), BKt (K-tile). QKV: <256,64>; proj: <64,128>
// (8 K-iters, 48KB LDS, 3 blocks/CU, grid 512 = 1 round).
// ---------------------------------------------------------------------------
template<int BNt, int BKt>
__global__ __launch_bounds__(256, 2) void gemm_bt_bias(
    const bf16_t* __restrict__ Abf,   // used when flag==1 (bf16 input)
    const bf16_t* __restrict__ Aalt,  // used when flag==0 (canonicalized)
    const bf16_t* __restrict__ Bt,
    const bf16_t* __restrict__ biasbf,
    const bf16_t* __restrict__ biasalt,
    void* __restrict__ C,
    int M, int N, int K,
    int force_bf16, const uint4* __restrict__ det)
{
    constexpr int BMt = 128;
    constexpr int NF  = BNt / 32;     // n-frags per wave (wave tile 64 x BNt/2)
    constexpr int LPR = BKt / 8;      // 16B chunks (lanes) per row
    constexpr int CM  = LPR - 1;      // chunk/swizzle mask
    constexpr int RPL = 64 / LPR;     // rows per global_load_lds
    constexpr int SL  = BKt / 32;     // K-slices per tile
    __shared__ __align__(16) bf16_t As[BMt * BKt];
    __shared__ __align__(16) bf16_t Bs[BNt * BKt];

    const int flag = detect_bf16(det);
    const bf16_t* A    = flag ? Abf    : Aalt;
    const bf16_t* bias = flag ? biasbf : biasalt;
    const int obf = force_bf16 | flag;

    const int tid  = threadIdx.x;
    const int wave = tid >> 6;
    const int lane = tid & 63;
    const int quad = lane >> 4;
    const int n16  = lane & 15;
    const int m0 = blockIdx.y * BMt;
    const int n0 = blockIdx.x * BNt;
    const int wm = (wave >> 1) * 64;
    const int wn = (wave & 1) * (BNt / 2);

    floatx4 acc[4][NF] = {};

    const int lr   = lane / LPR;      // local row within a load
    const int lc16 = lane % LPR;      // stored chunk slot

    for (int k0 = 0; k0 < K; k0 += BKt) {
        #pragma unroll
        for (int t = 0; t < (BMt / 4) / RPL; ++t) {
            const int row0 = wave * (BMt / 4) + t * RPL;
            const int g = (lc16 ^ ((row0 + lr) & CM)) * 8;
            const bf16_t* ga = A + (size_t)(m0 + row0 + lr) * K + k0 + g;
            __builtin_amdgcn_global_load_lds(
                (const __attribute__((address_space(1))) void*)ga,
                (__attribute__((address_space(3))) void*)(As + row0 * BKt),
                16, 0, 0);
        }
        #pragma unroll
        for (int t = 0; t < (BNt / 4) / RPL; ++t) {
            const int row0 = wave * (BNt / 4) + t * RPL;
            const int g = (lc16 ^ ((row0 + lr) & CM)) * 8;
            const bf16_t* gb = Bt + (size_t)(n0 + row0 + lr) * K + k0 + g;
            __builtin_amdgcn_global_load_lds(
                (const __attribute__((address_space(1))) void*)gb,
                (__attribute__((address_space(3))) void*)(Bs + row0 * BKt),
                16, 0, 0);
        }
        __syncthreads();

        // fragment rows: row&CM == n16&CM; want global chunk (4s+quad)
        #pragma unroll
        for (int s = 0; s < SL; ++s) {
            const int ch = (((4 * s + quad) ^ (n16 & CM)) * 8);
            const bf16_t* pa = As + (wm + n16) * BKt + ch;
            const bf16_t* pb = Bs + (wn + n16) * BKt + ch;
            bf16x8 af[4], bfr[NF];
            #pragma unroll
            for (int ff = 0; ff < 4; ++ff)
                af[ff] = *(const bf16x8*)(pa + ff * 16 * BKt);
            #pragma unroll
            for (int ff = 0; ff < NF; ++ff)
                bfr[ff] = *(const bf16x8*)(pb + ff * 16 * BKt);
            #pragma unroll
            for (int mf = 0; mf < 4; ++mf)
                #pragma unroll
                for (int nf = 0; nf < NF; ++nf)
                    acc[mf][nf] = __builtin_amdgcn_mfma_f32_16x16x32_bf16(
                        af[mf], bfr[nf], acc[mf][nf], 0, 0, 0);
        }
        __syncthreads();
    }

    const int col   = n0 + wn + n16;
    const int rbase = m0 + wm + quad * 4;
    #pragma unroll
    for (int nf = 0; nf < NF; ++nf) {
        const float bv = (float)bias[col + nf * 16];
        #pragma unroll
        for (int mf = 0; mf < 4; ++mf) {
            #pragma unroll
            for (int r = 0; r < 4; ++r) {
                const size_t idx =
                    (size_t)(rbase + mf * 16 + r) * N + col + nf * 16;
                const float val = acc[mf][nf][r] + bv;
                if (obf) ((bf16_t*)C)[idx] = (bf16_t)val;
                else     ((float*)C)[idx]  = val;
            }
        }
    }
}

// ---------------------------------------------------------------------------
// MFMA flash attention, R10: 4 chunks of 80 keys. LDS 36,864B -> 4 blocks/CU
// -> all 1024 blocks co-resident (1 round). Prefetch: V regs for hc+1 load
// during QK/softmax; K global_load_lds for hc+1 issued during PV.
// PV K-dim 80 -> 3 slices of 32 with Vt/Pst cols 80..95 zeroed once.
// ---------------------------------------------------------------------------
#define CW   80
#define NCH  4
#define VT_S 104
#define P_S  104

__global__ __launch_bounds__(256) void attn_mfma(
    const bf16_t* __restrict__ qkv,
    bf16_t* __restrict__ attn_out)
{
    __shared__ __align__(16) bf16_t Ks[CW * 64];       // 10240 B
    __shared__ __align__(16) bf16_t Vt[64 * VT_S];     // 13312 B
    __shared__ __align__(16) bf16_t Pst[4][16 * P_S];  // 13312 B

    const int tid  = threadIdx.x;
    const int wave = tid >> 6;
    const int lane = tid & 63;
    const int quad = lane >> 4;
    const int n16  = lane & 15;

    const int i0 = blockIdx.x * 64;
    const int h  = blockIdx.y;
    const int b  = blockIdx.z;
    const size_t rowbase = (size_t)b * SEQ_T;
    const int kbase  = i0 - 256;          // strip col c -> key j = kbase + c
    const int iw     = 16 * wave;
    const int climit = 256 - i0;          // j >= 0  <=>  c >= climit

    // Q A-frags
    const bf16_t* Qg = qkv + (rowbase + i0 + iw + n16) * (3 * EMB) + h * HDIM;
    bf16x8 qf[2];
    qf[0] = *(const bf16x8*)(Qg + quad * 8);
    qf[1] = *(const bf16x8*)(Qg + 32 + quad * 8);

    // zero the PV pad columns (written nowhere else; read by slice ks=2)
    for (int i = tid; i < 1024; i += 256)
        Vt[(i >> 4) * VT_S + 80 + (i & 15)] = (bf16_t)0.f;
    for (int i = tid; i < 1024; i += 256)
        Pst[i >> 8][((i >> 4) & 15) * P_S + 80 + (i & 15)] = (bf16_t)0.f;

    floatx4 Oac[4] = {};
    float m_run[4], l_run[4];
    #pragma unroll
    for (int rr = 0; rr < 4; ++rr) { m_run[rr] = -3.0e38f; l_run[rr] = 0.f; }

    bf16x8 vreg[3];

    // --- V chunk -> regs (640 bf16x8 vecs; threads 0..127 take a 3rd) ---
    auto loadV = [&](int hc) {
        const int cbase = hc * CW;
        #pragma unroll
        for (int t = 0; t < 3; ++t) {
            const int idx = tid + 256 * t;
            if (idx < 640) {
                const int lc = idx >> 3;
                const int d0 = (idx & 7) * 8;
                int j = kbase + cbase + lc; if (j < 0) j = 0;
                vreg[t] = *(const bf16x8*)(qkv + (rowbase + j) * (3 * EMB)
                                           + 2 * EMB + h * HDIM + d0);
            }
        }
    };
    // --- K chunk -> LDS (10 loads of 8 rows; waves 0,1 take 3, waves 2,3
    // take 2). Source-address swizzle: slot (lane&7) <- chunk (lane&7)^(row&7).
    auto stageK = [&](int hc) {
        const int cbase = hc * CW;
        for (int t = wave; t < 10; t += 4) {
            const int lc0 = t * 8;
            const int lcL = lc0 + (lane >> 3);
            int j = kbase + cbase + lcL; if (j < 0) j = 0;
            const int g = (lane & 7) ^ (lane >> 3);
            const bf16_t* src = qkv + (rowbase + j) * (3 * EMB)
                                + EMB + h * HDIM + g * 8;
            __builtin_amdgcn_global_load_lds(
                (const __attribute__((address_space(1))) void*)src,
                (__attribute__((address_space(3))) void*)(Ks + lc0 * 64),
                16, 0, 0);
        }
    };
    // --- transpose V regs -> Vt LDS ---
    auto writeVt = [&]() {
        #pragma unroll
        for (int t = 0; t < 3; ++t) {
            const int idx = tid + 256 * t;
            if (idx < 640) {
                const int lc = idx >> 3;
                const int d0 = (idx & 7) * 8;
                #pragma unroll
                for (int e = 0; e < 8; ++e)
                    Vt[(d0 + e) * VT_S + lc] = vreg[t][e];
            }
        }
    };

    loadV(0);
    stageK(0);

    for (int hc = 0; hc < NCH; ++hc) {
        const int cbase = hc * CW;

        __syncthreads();   // A: K(hc) staged; prev PV done (Vt/Pst free)
        writeVt();
        __syncthreads();   // B: Vt visible

        if (hc < NCH - 1) loadV(hc + 1);   // flies during QK/softmax

        // --- QK^T: 5 tiles of 16 keys x 2 K-slices ---
        floatx4 sc[5];
        #pragma unroll
        for (int tt = 0; tt < 5; ++tt) {
            sc[tt] = (floatx4){0.f, 0.f, 0.f, 0.f};
            #pragma unroll
            for (int s2 = 0; s2 < 2; ++s2) {
                const int lc = 16 * tt + n16;
                const int ch = (4 * s2 + quad) ^ (lc & 7);
                const bf16x8 kf = *(const bf16x8*)(Ks + lc * 64 + ch * 8);
                sc[tt] = __builtin_amdgcn_mfma_f32_16x16x32_bf16(
                    qf[s2], kf, sc[tt], 0, 0, 0);
            }
        }

        // --- mask + scale ---
        #pragma unroll
        for (int tt = 0; tt < 5; ++tt) {
            const int c  = cbase + 16 * tt + n16;
            const int cw = c - iw;
            #pragma unroll
            for (int rr = 0; rr < 4; ++rr) {
                const int r = quad * 4 + rr;
                const bool valid = (cw > r) && (cw <= r + 256) && (c >= climit);
                sc[tt][rr] = valid ? sc[tt][rr] * SCALE_F : -3.0e38f;
            }
        }

        // --- chunk row-max + online-softmax update ---
        float cm[4];
        #pragma unroll
        for (int rr = 0; rr < 4; ++rr) {
            cm[rr] = -3.0e38f;
            #pragma unroll
            for (int tt = 0; tt < 5; ++tt) cm[rr] = fmaxf(cm[rr], sc[tt][rr]);
            #pragma unroll
            for (int m = 8; m >= 1; m >>= 1)
                cm[rr] = fmaxf(cm[rr], __shfl_xor(cm[rr], m, 64));
        }
        #pragma unroll
        for (int rr = 0; rr < 4; ++rr) {
            const float mnew  = fmaxf(m_run[rr], cm[rr]);
            const float alpha = __expf(m_run[rr] - mnew);
            m_run[rr] = mnew;
            l_run[rr] *= alpha;
            #pragma unroll
            for (int nt = 0; nt < 4; ++nt) Oac[nt][rr] *= alpha;
        }

        // --- exp + sum + P strip ---
        float psum[4] = {0.f, 0.f, 0.f, 0.f};
        #pragma unroll
        for (int tt = 0; tt < 5; ++tt) {
            #pragma unroll
            for (int rr = 0; rr < 4; ++rr) {
                const float s = sc[tt][rr];
                const float e = (s > -1.0e38f) ? __expf(s - m_run[rr]) : 0.f;
                psum[rr] += e;
                Pst[wave][(quad * 4 + rr) * P_S + 16 * tt + n16] = (bf16_t)e;
            }
        }
        #pragma unroll
        for (int rr = 0; rr < 4; ++rr) {
            #pragma unroll
            for (int m = 8; m >= 1; m >>= 1)
                psum[rr] += __shfl_xor(psum[rr], m, 64);
            l_run[rr] += psum[rr];
        }

        __syncthreads();   // C: Pst visible; QK done reading Ks

        if (hc < NCH - 1) stageK(hc + 1);  // flies during PV

        // --- PV: 3 K-slices of 32 (cols 80..95 are zero pad) ---
        #pragma unroll
        for (int ks = 0; ks < 3; ++ks) {
            const bf16x8 paf = *(const bf16x8*)(
                &Pst[wave][n16 * P_S + ks * 32 + quad * 8]);
            #pragma unroll
            for (int nt = 0; nt < 4; ++nt) {
                const bf16x8 vbf = *(const bf16x8*)(
                    Vt + (nt * 16 + n16) * VT_S + ks * 32 + quad * 8);
                Oac[nt] = __builtin_amdgcn_mfma_f32_16x16x32_bf16(
                    paf, vbf, Oac[nt], 0, 0, 0);
            }
        }
    }

    #pragma unroll
    for (int rr = 0; rr < 4; ++rr) {
        const float rden = 1.0f / l_run[rr];
        const size_t row = rowbase + i0 + iw + quad * 4 + rr;
        #pragma unroll
        for (int nt = 0; nt < 4; ++nt) {
            attn_out[row * EMB + h * HDIM + nt * 16 + n16] =
                (bf16_t)(Oac[nt][rr] * rden);
        }
    }
}

// ---------------------------------------------------------------------------
extern "C" void kernel_launch(void* const* d_in, const int* in_sizes, int n_in,
                              void* d_out, int out_size, void* d_ws, size_t ws_size,
                              hipStream_t stream)
{
    const void* hidden = d_in[0];
    const void* w_attn = d_in[1];
    const void* b_attn = d_in[2];
    const void* w_proj = d_in[3];
    const void* b_proj = d_in[4];

    char* ws = (char*)d_ws;
    bf16_t* Wt_attn = (bf16_t*)(ws);                       // [3072][1024]
    bf16_t* Wt_proj = (bf16_t*)(ws + (6u << 20));          // [1024][1024]
    bf16_t* qkv     = (bf16_t*)(ws + (8u << 20));          // [4096][3072]
    bf16_t* attn_o  = (bf16_t*)(ws + (32u << 20));         // [4096][1024]
    bf16_t* Hc      = (bf16_t*)(ws + (40u << 20));         // [4096][1024]
    bf16_t* bb_attn = (bf16_t*)(ws + (48u << 20));
    bf16_t* bb_proj = (bf16_t*)(ws + (48u << 20) + 8192);

    const uint4* det = (const uint4*)hidden;

    prologue<<<5124, 256, 0, stream>>>(hidden, Hc, b_attn, bb_attn,
                                       b_proj, bb_proj,
                                       w_attn, Wt_attn, w_proj, Wt_proj);

    gemm_bt_bias<256, 64><<<dim3(3072 / 256, 4096 / 128), 256, 0, stream>>>(
        (const bf16_t*)hidden, Hc, Wt_attn,
        (const bf16_t*)b_attn, bb_attn, qkv, 4096, 3072, 1024, 1, det);

    attn_mfma<<<dim3(SEQ_T / 64, NHEAD, 2), 256, 0, stream>>>(qkv, attn_o);

    gemm_bt_bias<64, 128><<<dim3(1024 / 64, 4096 / 128), 256, 0, stream>>>(
        attn_o, attn_o, Wt_proj,
        (const bf16_t*)b_proj, bb_proj, (void*)d_out, 4096, 1024, 1024, 0, det);
}

// Round 11
// 165.942 us; speedup vs baseline: 1.8516x; 1.0154x over previous
//
#include <hip/hip_runtime.h>

// ---------------------------------------------------------------------------
// MaskedMultiHeadAttention: B=2, T=2048, E=1024, H=16, D=64, WINDOW=256
//
// R11: QKV GEMM BNt 256 -> 192: grid 384 -> 512 blocks = exactly 2/CU.
// At 384, half the CUs carried 2 blocks (critical path) while half carried 1
// and idled -> per-CU critical path 2.0 block-units; even 512 gives 1.5.
// Proj <64,128>, attention (4x80 chunks, 4 blocks/CU), prologue unchanged.
// ---------------------------------------------------------------------------

typedef __bf16 bf16_t;
typedef bf16_t bf16x8 __attribute__((ext_vector_type(8)));
typedef bf16_t bf16x4 __attribute__((ext_vector_type(4)));
typedef float  floatx4 __attribute__((ext_vector_type(4)));

#define SEQ_T   2048
#define NHEAD   16
#define HDIM    64
#define EMB     1024
#define WIN     256
#define SCALE_F 0.125f

// ---------------------------------------------------------------------------
// Wave-uniform dtype detect: all waves read the same 1 KB of hidden.
// ---------------------------------------------------------------------------
__device__ __forceinline__ int detect_bf16(const uint4* __restrict__ det)
{
    const int lane = threadIdx.x & 63;
    const uint4 v = det[lane];
    int c = 0;
    #pragma unroll
    for (int e = 0; e < 4; ++e) {
        const unsigned int ex = ((&v.x)[e] >> 7) & 0xffu;
        c += (ex >= 100u && ex <= 150u) ? 1 : 0;
    }
    #pragma unroll
    for (int m = 32; m >= 1; m >>= 1) c += __shfl_xor(c, m, 64);
    return (c * 2 > 256) ? 1 : 0;
}

// ---------------------------------------------------------------------------
// Fused prologue (one launch): canon (fp32 mode only) + both transposes.
// ---------------------------------------------------------------------------
__global__ __launch_bounds__(256) void prologue(
    const void* __restrict__ hidden, bf16_t* __restrict__ Hc,
    const void* __restrict__ ba, bf16_t* __restrict__ bba,
    const void* __restrict__ bp, bf16_t* __restrict__ bbp,
    const void* __restrict__ wA, bf16_t* __restrict__ WtA,
    const void* __restrict__ wP, bf16_t* __restrict__ WtP)
{
    __shared__ __align__(16) bf16_t tile[64][68];
    const int f = detect_bf16((const uint4*)hidden);
    const int blk = blockIdx.x;

    if (blk < 4100) {                       // canonicalize path
        if (f) return;
        const float* src;
        bf16_t* dst;
        int base;
        if (blk < 4096)      { src = (const float*)hidden; dst = Hc;  base = blk * 1024; }
        else if (blk < 4099) { src = (const float*)ba;     dst = bba; base = (blk - 4096) * 1024; }
        else                 { src = (const float*)bp;     dst = bbp; base = 0; }
        const int i4 = base + threadIdx.x * 4;
        const float4 x = *(const float4*)(src + i4);
        bf16x4 v;
        v[0] = (bf16_t)x.x; v[1] = (bf16_t)x.y;
        v[2] = (bf16_t)x.z; v[3] = (bf16_t)x.w;
        *(bf16x4*)(dst + i4) = v;
        return;
    }

    int id = blk - 4100;
    const void* W; bf16_t* Wt; int N, bx, by;
    if (id < 768) { W = wA; Wt = WtA; N = 3072; bx = id % 48; by = id / 48; }
    else { id -= 768; W = wP; Wt = WtP; N = 1024; bx = id % 16; by = id / 16; }
    const int K = 1024;
    const int n0 = bx * 64;
    const int k0 = by * 64;
    const int tx = threadIdx.x & 15;
    const int ty = threadIdx.x >> 4;

    #pragma unroll
    for (int r = ty; r < 64; r += 16) {
        bf16x4 v;
        const size_t base = (size_t)(k0 + r) * N + n0 + tx * 4;
        if (f) {
            v = *(const bf16x4*)((const bf16_t*)W + base);
        } else {
            const float4 x = *(const float4*)((const float*)W + base);
            v[0] = (bf16_t)x.x; v[1] = (bf16_t)x.y;
            v[2] = (bf16_t)x.z; v[3] = (bf16_t)x.w;
        }
        *(bf16x4*)&tile[r][tx * 4] = v;
    }
    __syncthreads();
    #pragma unroll
    for (int r = ty; r < 64; r += 16) {
        bf16x4 v;
        v[0] = tile[tx * 4 + 0][r];
        v[1] = tile[tx * 4 + 1][r];
        v[2] = tile[tx * 4 + 2][r];
        v[3] = tile[tx * 4 + 3][r];
        *(bf16x4*)(Wt + (size_t)(n0 + r) * K + k0 + tx * 4) = v;
    }
}

// ---------------------------------------------------------------------------
// C[M][N] = A[M][K] @ Bt[N][K]^T + bias[N]   (bf16 in, fp32 accumulate)
// Verified K-loop: single-buffer global_load_lds + XOR source-address swizzle
// (stored slot s of row r holds global chunk s ^ (r & CM); LDS dest stays
// wave-uniform + lane*16) -> conflict-free fragment reads.
// Template: BNt (block N), BKt (K-tile). QKV: <192,64> (512 blocks = 2/CU
// even); proj: <64,128> (8 K-iters, 512 blocks).
// ---------------------------------------------------------------------------
template<int BNt, int BKt>
__global__ __launch_bounds__(256, 2) void gemm_bt_bias(
    const bf16_t* __restrict__ Abf,   // used when flag==1 (bf16 input)
    const bf16_t* __restrict__ Aalt,  // used when flag==0 (canonicalized)
    const bf16_t* __restrict__ Bt,
    const bf16_t* __restrict__ biasbf,
    const bf16_t* __restrict__ biasalt,
    void* __restrict__ C,
    int M, int N, int K,
    int force_bf16, const uint4* __restrict__ det)
{
    constexpr int BMt = 128;
    constexpr int NF  = BNt / 32;     // n-frags per wave (wave tile 64 x BNt/2)
    constexpr int LPR = BKt / 8;      // 16B chunks (lanes) per row
    constexpr int CM  = LPR - 1;      // chunk/swizzle mask
    constexpr int RPL = 64 / LPR;     // rows per global_load_lds
    constexpr int SL  = BKt / 32;     // K-slices per tile
    __shared__ __align__(16) bf16_t As[BMt * BKt];
    __shared__ __align__(16) bf16_t Bs[BNt * BKt];

    const int flag = detect_bf16(det);
    const bf16_t* A    = flag ? Abf    : Aalt;
    const bf16_t* bias = flag ? biasbf : biasalt;
    const int obf = force_bf16 | flag;

    const int tid  = threadIdx.x;
    const int wave = tid >> 6;
    const int lane = tid & 63;
    const int quad = lane >> 4;
    const int n16  = lane & 15;
    const int m0 = blockIdx.y * BMt;
    const int n0 = blockIdx.x * BNt;
    const int wm = (wave >> 1) * 64;
    const int wn = (wave & 1) * (BNt / 2);

    floatx4 acc[4][NF] = {};

    const int lr   = lane / LPR;      // local row within a load
    const int lc16 = lane % LPR;      // stored chunk slot

    for (int k0 = 0; k0 < K; k0 += BKt) {
        #pragma unroll
        for (int t = 0; t < (BMt / 4) / RPL; ++t) {
            const int row0 = wave * (BMt / 4) + t * RPL;
            const int g = (lc16 ^ ((row0 + lr) & CM)) * 8;
            const bf16_t* ga = A + (size_t)(m0 + row0 + lr) * K + k0 + g;
            __builtin_amdgcn_global_load_lds(
                (const __attribute__((address_space(1))) void*)ga,
                (__attribute__((address_space(3))) void*)(As + row0 * BKt),
                16, 0, 0);
        }
        #pragma unroll
        for (int t = 0; t < (BNt / 4) / RPL; ++t) {
            const int row0 = wave * (BNt / 4) + t * RPL;
            const int g = (lc16 ^ ((row0 + lr) & CM)) * 8;
            const bf16_t* gb = Bt + (size_t)(n0 + row0 + lr) * K + k0 + g;
            __builtin_amdgcn_global_load_lds(
                (const __attribute__((address_space(1))) void*)gb,
                (__attribute__((address_space(3))) void*)(Bs + row0 * BKt),
                16, 0, 0);
        }
        __syncthreads();

        // fragment rows: row&CM == n16&CM; want global chunk (4s+quad)
        #pragma unroll
        for (int s = 0; s < SL; ++s) {
            const int ch = (((4 * s + quad) ^ (n16 & CM)) * 8);
            const bf16_t* pa = As + (wm + n16) * BKt + ch;
            const bf16_t* pb = Bs + (wn + n16) * BKt + ch;
            bf16x8 af[4], bfr[NF];
            #pragma unroll
            for (int ff = 0; ff < 4; ++ff)
                af[ff] = *(const bf16x8*)(pa + ff * 16 * BKt);
            #pragma unroll
            for (int ff = 0; ff < NF; ++ff)
                bfr[ff] = *(const bf16x8*)(pb + ff * 16 * BKt);
            #pragma unroll
            for (int mf = 0; mf < 4; ++mf)
                #pragma unroll
                for (int nf = 0; nf < NF; ++nf)
                    acc[mf][nf] = __builtin_amdgcn_mfma_f32_16x16x32_bf16(
                        af[mf], bfr[nf], acc[mf][nf], 0, 0, 0);
        }
        __syncthreads();
    }

    const int col   = n0 + wn + n16;
    const int rbase = m0 + wm + quad * 4;
    #pragma unroll
    for (int nf = 0; nf < NF; ++nf) {
        const float bv = (float)bias[col + nf * 16];
        #pragma unroll
        for (int mf = 0; mf < 4; ++mf) {
            #pragma unroll
            for (int r = 0; r < 4; ++r) {
                const size_t idx =
                    (size_t)(rbase + mf * 16 + r) * N + col + nf * 16;
                const float val = acc[mf][nf][r] + bv;
                if (obf) ((bf16_t*)C)[idx] = (bf16_t)val;
                else     ((float*)C)[idx]  = val;
            }
        }
    }
}

// ---------------------------------------------------------------------------
// MFMA flash attention (R10): 4 chunks of 80 keys, 36KB LDS, 4 blocks/CU,
// V-reg and K-lds prefetch hidden under compute. PV pads cols 80..95 = 0.
// ---------------------------------------------------------------------------
#define CW   80
#define NCH  4
#define VT_S 104
#define P_S  104

__global__ __launch_bounds__(256) void attn_mfma(
    const bf16_t* __restrict__ qkv,
    bf16_t* __restrict__ attn_out)
{
    __shared__ __align__(16) bf16_t Ks[CW * 64];       // 10240 B
    __shared__ __align__(16) bf16_t Vt[64 * VT_S];     // 13312 B
    __shared__ __align__(16) bf16_t Pst[4][16 * P_S];  // 13312 B

    const int tid  = threadIdx.x;
    const int wave = tid >> 6;
    const int lane = tid & 63;
    const int quad = lane >> 4;
    const int n16  = lane & 15;

    const int i0 = blockIdx.x * 64;
    const int h  = blockIdx.y;
    const int b  = blockIdx.z;
    const size_t rowbase = (size_t)b * SEQ_T;
    const int kbase  = i0 - 256;
    const int iw     = 16 * wave;
    const int climit = 256 - i0;

    const bf16_t* Qg = qkv + (rowbase + i0 + iw + n16) * (3 * EMB) + h * HDIM;
    bf16x8 qf[2];
    qf[0] = *(const bf16x8*)(Qg + quad * 8);
    qf[1] = *(const bf16x8*)(Qg + 32 + quad * 8);

    for (int i = tid; i < 1024; i += 256)
        Vt[(i >> 4) * VT_S + 80 + (i & 15)] = (bf16_t)0.f;
    for (int i = tid; i < 1024; i += 256)
        Pst[i >> 8][((i >> 4) & 15) * P_S + 80 + (i & 15)] = (bf16_t)0.f;

    floatx4 Oac[4] = {};
    float m_run[4], l_run[4];
    #pragma unroll
    for (int rr = 0; rr < 4; ++rr) { m_run[rr] = -3.0e38f; l_run[rr] = 0.f; }

    bf16x8 vreg[3];

    auto loadV = [&](int hc) {
        const int cbase = hc * CW;
        #pragma unroll
        for (int t = 0; t < 3; ++t) {
            const int idx = tid + 256 * t;
            if (idx < 640) {
                const int lc = idx >> 3;
                const int d0 = (idx & 7) * 8;
                int j = kbase + cbase + lc; if (j < 0) j = 0;
                vreg[t] = *(const bf16x8*)(qkv + (rowbase + j) * (3 * EMB)
                                           + 2 * EMB + h * HDIM + d0);
            }
        }
    };
    auto stageK = [&](int hc) {
        const int cbase = hc * CW;
        for (int t = wave; t < 10; t += 4) {
            const int lc0 = t * 8;
            const int lcL = lc0 + (lane >> 3);
            int j = kbase + cbase + lcL; if (j < 0) j = 0;
            const int g = (lane & 7) ^ (lane >> 3);
            const bf16_t* src = qkv + (rowbase + j) * (3 * EMB)
                                + EMB + h * HDIM + g * 8;
            __builtin_amdgcn_global_load_lds(
                (const __attribute__((address_space(1))) void*)src,
                (__attribute__((address_space(3))) void*)(Ks + lc0 * 64),
                16, 0, 0);
        }
    };
    auto writeVt = [&]() {
        #pragma unroll
        for (int t = 0; t < 3; ++t) {
            const int idx = tid + 256 * t;
            if (idx < 640) {
                const int lc = idx >> 3;
                const int d0 = (idx & 7) * 8;
                #pragma unroll
                for (int e = 0; e < 8; ++e)
                    Vt[(d0 + e) * VT_S + lc] = vreg[t][e];
            }
        }
    };

    loadV(0);
    stageK(0);

    for (int hc = 0; hc < NCH; ++hc) {
        const int cbase = hc * CW;

        __syncthreads();   // A: K(hc) staged; prev PV done (Vt/Pst free)
        writeVt();
        __syncthreads();   // B: Vt visible

        if (hc < NCH - 1) loadV(hc + 1);   // flies during QK/softmax

        floatx4 sc[5];
        #pragma unroll
        for (int tt = 0; tt < 5; ++tt) {
            sc[tt] = (floatx4){0.f, 0.f, 0.f, 0.f};
            #pragma unroll
            for (int s2 = 0; s2 < 2; ++s2) {
                const int lc = 16 * tt + n16;
                const int ch = (4 * s2 + quad) ^ (lc & 7);
                const bf16x8 kf = *(const bf16x8*)(Ks + lc * 64 + ch * 8);
                sc[tt] = __builtin_amdgcn_mfma_f32_16x16x32_bf16(
                    qf[s2], kf, sc[tt], 0, 0, 0);
            }
        }

        #pragma unroll
        for (int tt = 0; tt < 5; ++tt) {
            const int c  = cbase + 16 * tt + n16;
            const int cw = c - iw;
            #pragma unroll
            for (int rr = 0; rr < 4; ++rr) {
                const int r = quad * 4 + rr;
                const bool valid = (cw > r) && (cw <= r + 256) && (c >= climit);
                sc[tt][rr] = valid ? sc[tt][rr] * SCALE_F : -3.0e38f;
            }
        }

        float cm[4];
        #pragma unroll
        for (int rr = 0; rr < 4; ++rr) {
            cm[rr] = -3.0e38f;
            #pragma unroll
            for (int tt = 0; tt < 5; ++tt) cm[rr] = fmaxf(cm[rr], sc[tt][rr]);
            #pragma unroll
            for (int m = 8; m >= 1; m >>= 1)
                cm[rr] = fmaxf(cm[rr], __shfl_xor(cm[rr], m, 64));
        }
        #pragma unroll
        for (int rr = 0; rr < 4; ++rr) {
            const float mnew  = fmaxf(m_run[rr], cm[rr]);
            const float alpha = __expf(m_run[rr] - mnew);
            m_run[rr] = mnew;
            l_run[rr] *= alpha;
            #pragma unroll
            for (int nt = 0; nt < 4; ++nt) Oac[nt][rr] *= alpha;
        }

        float psum[4] = {0.f, 0.f, 0.f, 0.f};
        #pragma unroll
        for (int tt = 0; tt < 5; ++tt) {
            #pragma unroll
            for (int rr = 0; rr < 4; ++rr) {
                const float s = sc[tt][rr];
                const float e = (s > -1.0e38f) ? __expf(s - m_run[rr]) : 0.f;
                psum[rr] += e;
                Pst[wave][(quad * 4 + rr) * P_S + 16 * tt + n16] = (bf16_t)e;
            }
        }
        #pragma unroll
        for (int rr = 0; rr < 4; ++rr) {
            #pragma unroll
            for (int m = 8; m >= 1; m >>= 1)
                psum[rr] += __shfl_xor(psum[rr], m, 64);
            l_run[rr] += psum[rr];
        }

        __syncthreads();   // C: Pst visible; QK done reading Ks

        if (hc < NCH - 1) stageK(hc + 1);  // flies during PV

        #pragma unroll
        for (int ks = 0; ks < 3; ++ks) {
            const bf16x8 paf = *(const bf16x8*)(
                &Pst[wave][n16 * P_S + ks * 32 + quad * 8]);
            #pragma unroll
            for (int nt = 0; nt < 4; ++nt) {
                const bf16x8 vbf = *(const bf16x8*)(
                    Vt + (nt * 16 + n16) * VT_S + ks * 32 + quad * 8);
                Oac[nt] = __builtin_amdgcn_mfma_f32_16x16x32_bf16(
                    paf, vbf, Oac[nt], 0, 0, 0);
            }
        }
    }

    #pragma unroll
    for (int rr = 0; rr < 4; ++rr) {
        const float rden = 1.0f / l_run[rr];
        const size_t row = rowbase + i0 + iw + quad * 4 + rr;
        #pragma unroll
        for (int nt = 0; nt < 4; ++nt) {
            attn_out[row * EMB + h * HDIM + nt * 16 + n16] =
                (bf16_t)(Oac[nt][rr] * rden);
        }
    }
}

// ---------------------------------------------------------------------------
extern "C" void kernel_launch(void* const* d_in, const int* in_sizes, int n_in,
                              void* d_out, int out_size, void* d_ws, size_t ws_size,
                              hipStream_t stream)
{
    const void* hidden = d_in[0];
    const void* w_attn = d_in[1];
    const void* b_attn = d_in[2];
    const void* w_proj = d_in[3];
    const void* b_proj = d_in[4];

    char* ws = (char*)d_ws;
    bf16_t* Wt_attn = (bf16_t*)(ws);                       // [3072][1024]
    bf16_t* Wt_proj = (bf16_t*)(ws + (6u << 20));          // [1024][1024]
    bf16_t* qkv     = (bf16_t*)(ws + (8u << 20));          // [4096][3072]
    bf16_t* attn_o  = (bf16_t*)(ws + (32u << 20));         // [4096][1024]
    bf16_t* Hc      = (bf16_t*)(ws + (40u << 20));         // [4096][1024]
    bf16_t* bb_attn = (bf16_t*)(ws + (48u << 20));
    bf16_t* bb_proj = (bf16_t*)(ws + (48u << 20) + 8192);

    const uint4* det = (const uint4*)hidden;

    prologue<<<5124, 256, 0, stream>>>(hidden, Hc, b_attn, bb_attn,
                                       b_proj, bb_proj,
                                       w_attn, Wt_attn, w_proj, Wt_proj);

    gemm_bt_bias<192, 64><<<dim3(3072 / 192, 4096 / 128), 256, 0, stream>>>(
        (const bf16_t*)hidden, Hc, Wt_attn,
        (const bf16_t*)b_attn, bb_attn, qkv, 4096, 3072, 1024, 1, det);

    attn_mfma<<<dim3(SEQ_T / 64, NHEAD, 2), 256, 0, stream>>>(qkv, attn_o);

    gemm_bt_bias<64, 128><<<dim3(1024 / 64, 4096 / 128), 256, 0, stream>>>(
        attn_o, attn_o, Wt_proj,
        (const bf16_t*)b_proj, bb_proj, (void*)d_out, 4096, 1024, 1024, 0, det);
}